// Round 1
// baseline (483.723 us; speedup 1.0000x reference)
//
#include <hip/hip_runtime.h>
#include <hip/hip_bf16.h>
#include <math.h>

// Problem constants (fixed by the reference)
#define BB 32
#define LL 768
#define DD 256
#define FF 256
#define TT 3072
#define TM 16   // rows (l positions) per block in the conv kernels

// ---------------------------------------------------------------------------
// Fused Conv1d(k=3, pad=1) + ReLU + LayerNorm  (+ optional linear->exp head)
// Block: 256 threads, one thread per output channel (col).
// Tile: TM=16 consecutive l positions of one batch row.
// ---------------------------------------------------------------------------
template <bool SECOND>
__global__ __launch_bounds__(256) void conv_ln_kernel(
    const float* __restrict__ in,      // [B, L, 256]
    const float* __restrict__ w,       // [3, 256, 256]  (K, Cin, Cout)
    const float* __restrict__ cbias,   // [256]
    const float* __restrict__ g,       // [256] LN gain
    const float* __restrict__ be,      // [256] LN bias
    const float* __restrict__ lin_w,   // [256] (SECOND only)
    const float* __restrict__ lin_b,   // [1]   (SECOND only)
    float* __restrict__ out_h,         // [B, L, 256] (first layer only)
    float* __restrict__ out_dur)       // [B, L]      (SECOND only: exp(dp))
{
    __shared__ float xs[TM + 2][DD];   // input rows l0-1 .. l0+TM
    __shared__ float red[4][TM][2];    // per-wave partials
    __shared__ float fin[TM][2];       // per-row (mu, rstd)

    const int tid = threadIdx.x;
    const int tiles_per_b = LL / TM;
    const int b  = blockIdx.x / tiles_per_b;
    const int l0 = (blockIdx.x % tiles_per_b) * TM;

    // Stage input rows (zero-pad at sequence edges)
    for (int r = 0; r < TM + 2; ++r) {
        int l = l0 - 1 + r;
        float v = 0.f;
        if (l >= 0 && l < LL) v = in[((size_t)b * LL + l) * DD + tid];
        xs[r][tid] = v;
    }
    __syncthreads();

    const int col = tid;
    float acc[TM];
    {
        float bias = cbias[col];
#pragma unroll
        for (int r = 0; r < TM; ++r) acc[r] = bias;
    }

    // K loop over input channels, 4 at a time (float4 LDS reads)
    for (int c4 = 0; c4 < DD / 4; ++c4) {
        float4 xv[TM + 2];
#pragma unroll
        for (int r = 0; r < TM + 2; ++r)
            xv[r] = *reinterpret_cast<const float4*>(&xs[r][c4 * 4]);
#pragma unroll
        for (int k = 0; k < 3; ++k) {
            const int cin = c4 * 4;
            const float w0 = w[(k * DD + cin + 0) * FF + col];
            const float w1 = w[(k * DD + cin + 1) * FF + col];
            const float w2 = w[(k * DD + cin + 2) * FF + col];
            const float w3 = w[(k * DD + cin + 3) * FF + col];
#pragma unroll
            for (int r = 0; r < TM; ++r) {
                float4 xr = xv[r + k];
                acc[r] = fmaf(xr.x, w0, acc[r]);
                acc[r] = fmaf(xr.y, w1, acc[r]);
                acc[r] = fmaf(xr.z, w2, acc[r]);
                acc[r] = fmaf(xr.w, w3, acc[r]);
            }
        }
    }

    // ReLU
#pragma unroll
    for (int r = 0; r < TM; ++r) acc[r] = fmaxf(acc[r], 0.f);

    // Per-row mean / var across the 256 cols
    const int wave = tid >> 6;
#pragma unroll
    for (int r = 0; r < TM; ++r) {
        float v = acc[r];
        float sum = v, sq = v * v;
        for (int off = 32; off > 0; off >>= 1) {
            sum += __shfl_down(sum, off, 64);
            sq  += __shfl_down(sq,  off, 64);
        }
        if ((tid & 63) == 0) { red[wave][r][0] = sum; red[wave][r][1] = sq; }
    }
    __syncthreads();
    if (tid < TM) {
        float sum = red[0][tid][0] + red[1][tid][0] + red[2][tid][0] + red[3][tid][0];
        float sq  = red[0][tid][1] + red[1][tid][1] + red[2][tid][1] + red[3][tid][1];
        float mu  = sum / FF;
        float var = sq / FF - mu * mu;
        fin[tid][0] = mu;
        fin[tid][1] = rsqrtf(var + 1e-5f);
    }
    __syncthreads();

    const float gv = g[col];
    const float bv = be[col];
    const float lwv = SECOND ? lin_w[col] : 0.f;

#pragma unroll
    for (int r = 0; r < TM; ++r) {
        float mu = fin[r][0], rstd = fin[r][1];
        float v = (acc[r] - mu) * rstd * gv + bv;
        if (!SECOND) {
            out_h[((size_t)b * LL + l0 + r) * FF + col] = v;
        } else {
            float p = v * lwv;
            for (int off = 32; off > 0; off >>= 1) p += __shfl_down(p, off, 64);
            if ((tid & 63) == 0) red[wave][r][0] = p;
        }
    }
    if (SECOND) {
        __syncthreads();
        if (tid < TM) {
            float dp = red[0][tid][0] + red[1][tid][0] + red[2][tid][0] + red[3][tid][0]
                     + lin_b[0];
            out_dur[(size_t)b * LL + l0 + tid] = expf(dp);
        }
    }
}

// ---------------------------------------------------------------------------
// dpo + cumsum + scatter idx map.  One block per batch row.
// idx_map[b][t] = l such that cum[l-1] <= t < cum[l];  -1 if t >= total.
// ---------------------------------------------------------------------------
__global__ __launch_bounds__(256) void scan_kernel(
    const int* __restrict__ target,    // [B, L]
    float* __restrict__ out_dpo,       // [B, L] (stored as float)
    int* __restrict__ idx_map)         // [B, T]
{
    __shared__ int tsum[256];
    const int b = blockIdx.x, tid = threadIdx.x;

    const int l = 3 * tid;
    const int v0 = target[b * LL + l];
    const int v1 = target[b * LL + l + 1];
    const int v2 = target[b * LL + l + 2];
    out_dpo[b * LL + l]     = (float)v0;
    out_dpo[b * LL + l + 1] = (float)v1;
    out_dpo[b * LL + l + 2] = (float)v2;

    const int s0 = v0, s1 = v0 + v1, s2 = v0 + v1 + v2;
    tsum[tid] = s2;
    __syncthreads();
    // Hillis-Steele inclusive scan over per-thread sums
    for (int off = 1; off < 256; off <<= 1) {
        int x = (tid >= off) ? tsum[tid - off] : 0;
        __syncthreads();
        tsum[tid] += x;
        __syncthreads();
    }
    const int excl = tsum[tid] - s2;

    // init idx map to "masked"
    for (int t = tid; t < TT; t += 256) idx_map[b * TT + t] = -1;
    __syncthreads();

    const int c0 = excl + s0, c1 = excl + s1, c2 = excl + s2;
    for (int t = excl; t < c0 && t < TT; ++t) idx_map[b * TT + t] = l;
    for (int t = c0;   t < c1 && t < TT; ++t) idx_map[b * TT + t] = l + 1;
    for (int t = c1;   t < c2 && t < TT; ++t) idx_map[b * TT + t] = l + 2;
}

// ---------------------------------------------------------------------------
// Gather: out[b,t,:] = x[b, idx_map[b][t], :]  (zeros when masked)
// One wave per (b,t) row; lane i copies float4 i.
// ---------------------------------------------------------------------------
__global__ __launch_bounds__(256) void gather_kernel(
    const float* __restrict__ x,       // [B, L, 256]
    const int* __restrict__ idx_map,   // [B, T]
    float* __restrict__ out)           // [B, T, 256]
{
    const int wv = threadIdx.x >> 6, lane = threadIdx.x & 63;
    const int row = blockIdx.x * 4 + wv;          // row in [0, B*T)
    const int b = row / TT, t = row - b * TT;
    const int idx = idx_map[b * TT + t];
    float4 val = make_float4(0.f, 0.f, 0.f, 0.f);
    if (idx >= 0)
        val = reinterpret_cast<const float4*>(x)[(size_t)(b * LL + idx) * (DD / 4) + lane];
    reinterpret_cast<float4*>(out)[(size_t)row * (DD / 4) + lane] = val;
}

// ---------------------------------------------------------------------------
extern "C" void kernel_launch(void* const* d_in, const int* in_sizes, int n_in,
                              void* d_out, int out_size, void* d_ws, size_t ws_size,
                              hipStream_t stream)
{
    const float* x      = (const float*)d_in[0];
    const int*   target = (const int*)  d_in[1];
    // d_in[2] = mel_max_length (== TT, hardcoded)
    const float* c1w = (const float*)d_in[3];
    const float* c1b = (const float*)d_in[4];
    const float* g1  = (const float*)d_in[5];
    const float* b1  = (const float*)d_in[6];
    const float* c2w = (const float*)d_in[7];
    const float* c2b = (const float*)d_in[8];
    const float* g2  = (const float*)d_in[9];
    const float* b2  = (const float*)d_in[10];
    const float* lw  = (const float*)d_in[11];
    const float* lb  = (const float*)d_in[12];

    float* out0    = (float*)d_out;                       // [B, T, 256]
    float* out_dpo = out0 + (size_t)BB * TT * DD;         // [B, L]
    float* out_dur = out_dpo + (size_t)BB * LL;           // [B, L]

    float* h1      = (float*)d_ws;                        // [B, L, 256]
    int*   idx_map = (int*)((char*)d_ws + (size_t)BB * LL * FF * sizeof(float));

    const int conv_grid = BB * (LL / TM);
    conv_ln_kernel<false><<<conv_grid, 256, 0, stream>>>(
        x, c1w, c1b, g1, b1, nullptr, nullptr, h1, nullptr);
    conv_ln_kernel<true><<<conv_grid, 256, 0, stream>>>(
        h1, c2w, c2b, g2, b2, lw, lb, nullptr, out_dur);
    scan_kernel<<<BB, 256, 0, stream>>>(target, out_dpo, idx_map);
    gather_kernel<<<BB * TT / 4, 256, 0, stream>>>(x, idx_map, out0);
}

// Round 2
// 266.149 us; speedup vs baseline: 1.8175x; 1.8175x over previous
//
#include <hip/hip_runtime.h>
#include <hip/hip_bf16.h>
#include <math.h>

// Problem constants (fixed by the reference)
#define BB 32
#define LL 768
#define DD 256
#define FF 256
#define TT 3072
#define MT 32              // output rows (l positions) per conv block
#define AP 264             // padded A-tile row length in bf16 elems (256 + 8)

typedef __attribute__((ext_vector_type(8))) short bf16x8;
typedef __attribute__((ext_vector_type(4))) float f32x4;

__device__ inline unsigned short f2b(float f) {
    union { float f; unsigned u; } v; v.f = f;
    unsigned r = (v.u + 0x7FFF + ((v.u >> 16) & 1)) >> 16;  // RNE
    return (unsigned short)r;
}

// ---------------------------------------------------------------------------
// Weight prep: wT[n][kappa] = bf16(w[kappa/256][kappa%256][n]),  kappa in [0,768)
// blocks 0..255 -> conv1, 256..511 -> conv2
// ---------------------------------------------------------------------------
__global__ __launch_bounds__(256) void prep_w_kernel(
    const float* __restrict__ w1, const float* __restrict__ w2,
    unsigned short* __restrict__ wT1, unsigned short* __restrict__ wT2)
{
    const int n = blockIdx.x & 255;
    const float* w = (blockIdx.x < 256) ? w1 : w2;
    unsigned short* o = (blockIdx.x < 256) ? wT1 : wT2;
    for (int k = threadIdx.x; k < 768; k += 256)
        o[(size_t)n * 768 + k] = f2b(w[(size_t)k * 256 + n]);
}

// ---------------------------------------------------------------------------
// Fused Conv1d(k=3,pad=1) + ReLU + LayerNorm (+ linear->exp head on SECOND)
// as a bf16 MFMA GEMM: M-tile=32 rows, N=256 (full width), K=768.
// Block: 256 threads = 4 waves; wave w covers cols [64w, 64w+64).
// A-tile: x rows l0-1 .. l0+32 (34 x 256) in LDS as bf16, row-padded.
// B: streamed from pre-transposed bf16 weights wT[256][768].
// ---------------------------------------------------------------------------
template <bool SECOND>
__global__ __launch_bounds__(256) void conv_mfma_kernel(
    const void* __restrict__ in_,              // conv1: float*, conv2: bf16(ushort)*
    const unsigned short* __restrict__ wT,     // [256][768] bf16
    const float* __restrict__ cbias,           // [256]
    const float* __restrict__ g,               // [256]
    const float* __restrict__ be,              // [256]
    const float* __restrict__ lin_w,           // [256] (SECOND)
    const float* __restrict__ lin_b,           // [1]   (SECOND)
    unsigned short* __restrict__ out_h,        // bf16 [B,L,256] (first layer)
    float* __restrict__ out_dur)               // [B,L] (SECOND)
{
    __shared__ union {
        unsigned short As[34 * AP];            // 17.95 KB
        float outs[MT * 257];                  // 32.9 KB
    } sm;
    __shared__ float red[4][MT][2];
    __shared__ float fin[MT][2];

    const int tid = threadIdx.x;
    const int b  = blockIdx.x / (LL / MT);
    const int l0 = (blockIdx.x % (LL / MT)) * MT;

    // ---- stage A-tile (34 rows x 256 ch) as bf16, zero-padded at edges ----
    {
        const int c2 = (tid & 127) * 2;
        for (int r = tid >> 7; r < 34; r += 2) {
            const int l = l0 - 1 + r;
            unsigned short h0 = 0, h1 = 0;
            if (l >= 0 && l < LL) {
                if (!SECOND) {
                    const float2 v = *reinterpret_cast<const float2*>(
                        (const float*)in_ + ((size_t)b * LL + l) * DD + c2);
                    h0 = f2b(v.x); h1 = f2b(v.y);
                } else {
                    const ushort2 v = *reinterpret_cast<const ushort2*>(
                        (const unsigned short*)in_ + ((size_t)b * LL + l) * DD + c2);
                    h0 = v.x; h1 = v.y;
                }
            }
            *reinterpret_cast<unsigned int*>(&sm.As[r * AP + c2]) =
                (unsigned)h0 | ((unsigned)h1 << 16);
        }
    }
    __syncthreads();

    const int wave = tid >> 6, lane = tid & 63;
    const int quad = lane >> 4, l16 = lane & 15;

    f32x4 acc[2][4] = {};   // [m-tile][n-tile], 32 fp32/lane

    // ---- K loop: 24 steps of 32; kappa = kconv*256 + cin ----
    for (int step = 0; step < 24; ++step) {
        const int kc   = step >> 3;          // conv tap 0..2
        const int cin0 = (step & 7) * 32;    // channel offset within tap
        bf16x8 a[2], bb[4];
#pragma unroll
        for (int mt = 0; mt < 2; ++mt) {
            const int row = mt * 16 + l16 + kc;   // A row in tile coords
            a[mt] = *reinterpret_cast<const bf16x8*>(
                &sm.As[row * AP + cin0 + quad * 8]);
        }
#pragma unroll
        for (int nt = 0; nt < 4; ++nt) {
            const int n = wave * 64 + nt * 16 + l16;
            bb[nt] = *reinterpret_cast<const bf16x8*>(
                &wT[(size_t)n * 768 + step * 32 + quad * 8]);
        }
#pragma unroll
        for (int mt = 0; mt < 2; ++mt)
#pragma unroll
            for (int nt = 0; nt < 4; ++nt)
                acc[mt][nt] = __builtin_amdgcn_mfma_f32_16x16x32_bf16(
                    a[mt], bb[nt], acc[mt][nt], 0, 0, 0);
    }
    __syncthreads();   // A-tile dead; reuse LDS for the output tile

    // ---- scatter accumulators to LDS (C/D layout: col=lane&15, row=quad*4+reg) ----
#pragma unroll
    for (int mt = 0; mt < 2; ++mt)
#pragma unroll
        for (int nt = 0; nt < 4; ++nt)
#pragma unroll
            for (int r = 0; r < 4; ++r) {
                const int row = mt * 16 + quad * 4 + r;
                const int col = wave * 64 + nt * 16 + l16;
                sm.outs[row * 257 + col] = acc[mt][nt][r];
            }
    __syncthreads();

    // ---- LayerNorm over the 256 cols for each of the 32 rows ----
    const int col = tid;
    const float biasv = cbias[col];
    float vv[MT];
#pragma unroll
    for (int r = 0; r < MT; ++r)
        vv[r] = fmaxf(sm.outs[r * 257 + col] + biasv, 0.f);   // +bias, ReLU

#pragma unroll
    for (int r = 0; r < MT; ++r) {
        float v = vv[r];
        float sum = v, sq = v * v;
        for (int off = 32; off > 0; off >>= 1) {
            sum += __shfl_down(sum, off, 64);
            sq  += __shfl_down(sq,  off, 64);
        }
        if (lane == 0) { red[wave][r][0] = sum; red[wave][r][1] = sq; }
    }
    __syncthreads();
    if (tid < MT) {
        const float sum = red[0][tid][0] + red[1][tid][0] + red[2][tid][0] + red[3][tid][0];
        const float sq  = red[0][tid][1] + red[1][tid][1] + red[2][tid][1] + red[3][tid][1];
        const float mu  = sum / FF;
        const float var = sq / FF - mu * mu;
        fin[tid][0] = mu;
        fin[tid][1] = rsqrtf(var + 1e-5f);
    }
    __syncthreads();

    const float gv  = g[col];
    const float bv  = be[col];
    const float lwv = SECOND ? lin_w[col] : 0.f;

#pragma unroll
    for (int r = 0; r < MT; ++r) {
        const float v = (vv[r] - fin[r][0]) * fin[r][1] * gv + bv;
        if (!SECOND) {
            out_h[((size_t)b * LL + l0 + r) * FF + col] = f2b(v);
        } else {
            float p = v * lwv;
            for (int off = 32; off > 0; off >>= 1) p += __shfl_down(p, off, 64);
            if (lane == 0) red[wave][r][0] = p;
        }
    }
    if (SECOND) {
        __syncthreads();
        if (tid < MT) {
            const float dp = red[0][tid][0] + red[1][tid][0] + red[2][tid][0]
                           + red[3][tid][0] + lin_b[0];
            out_dur[(size_t)b * LL + l0 + tid] = expf(dp);
        }
    }
}

// ---------------------------------------------------------------------------
// dpo + cumsum + scatter idx map.  One block per batch row.
// ---------------------------------------------------------------------------
__global__ __launch_bounds__(256) void scan_kernel(
    const int* __restrict__ target,    // [B, L]
    float* __restrict__ out_dpo,       // [B, L] (stored as float)
    int* __restrict__ idx_map)         // [B, T]
{
    __shared__ int tsum[256];
    const int b = blockIdx.x, tid = threadIdx.x;

    const int l = 3 * tid;
    const int v0 = target[b * LL + l];
    const int v1 = target[b * LL + l + 1];
    const int v2 = target[b * LL + l + 2];
    out_dpo[b * LL + l]     = (float)v0;
    out_dpo[b * LL + l + 1] = (float)v1;
    out_dpo[b * LL + l + 2] = (float)v2;

    const int s0 = v0, s1 = v0 + v1, s2 = v0 + v1 + v2;
    tsum[tid] = s2;
    __syncthreads();
    for (int off = 1; off < 256; off <<= 1) {
        int x = (tid >= off) ? tsum[tid - off] : 0;
        __syncthreads();
        tsum[tid] += x;
        __syncthreads();
    }
    const int excl = tsum[tid] - s2;

    for (int t = tid; t < TT; t += 256) idx_map[b * TT + t] = -1;
    __syncthreads();

    const int c0 = excl + s0, c1 = excl + s1, c2 = excl + s2;
    for (int t = excl; t < c0 && t < TT; ++t) idx_map[b * TT + t] = l;
    for (int t = c0;   t < c1 && t < TT; ++t) idx_map[b * TT + t] = l + 1;
    for (int t = c1;   t < c2 && t < TT; ++t) idx_map[b * TT + t] = l + 2;
}

// ---------------------------------------------------------------------------
// Gather: out[b,t,:] = x[b, idx_map[b][t], :]  (zeros when masked)
// ---------------------------------------------------------------------------
__global__ __launch_bounds__(256) void gather_kernel(
    const float* __restrict__ x,       // [B, L, 256]
    const int* __restrict__ idx_map,   // [B, T]
    float* __restrict__ out)           // [B, T, 256]
{
    const int wv = threadIdx.x >> 6, lane = threadIdx.x & 63;
    const int row = blockIdx.x * 4 + wv;          // row in [0, B*T)
    const int b = row / TT, t = row - b * TT;
    const int idx = idx_map[b * TT + t];
    float4 val = make_float4(0.f, 0.f, 0.f, 0.f);
    if (idx >= 0)
        val = reinterpret_cast<const float4*>(x)[(size_t)(b * LL + idx) * (DD / 4) + lane];
    reinterpret_cast<float4*>(out)[(size_t)row * (DD / 4) + lane] = val;
}

// ---------------------------------------------------------------------------
extern "C" void kernel_launch(void* const* d_in, const int* in_sizes, int n_in,
                              void* d_out, int out_size, void* d_ws, size_t ws_size,
                              hipStream_t stream)
{
    const float* x      = (const float*)d_in[0];
    const int*   target = (const int*)  d_in[1];
    const float* c1w = (const float*)d_in[3];
    const float* c1b = (const float*)d_in[4];
    const float* g1  = (const float*)d_in[5];
    const float* b1  = (const float*)d_in[6];
    const float* c2w = (const float*)d_in[7];
    const float* c2b = (const float*)d_in[8];
    const float* g2  = (const float*)d_in[9];
    const float* b2  = (const float*)d_in[10];
    const float* lw  = (const float*)d_in[11];
    const float* lb  = (const float*)d_in[12];

    float* out0    = (float*)d_out;                       // [B, T, 256]
    float* out_dpo = out0 + (size_t)BB * TT * DD;         // [B, L]
    float* out_dur = out_dpo + (size_t)BB * LL;           // [B, L]

    // workspace layout
    char* ws = (char*)d_ws;
    unsigned short* wT1 = (unsigned short*)ws;                 ws += (size_t)256 * 768 * 2;
    unsigned short* wT2 = (unsigned short*)ws;                 ws += (size_t)256 * 768 * 2;
    unsigned short* h1b = (unsigned short*)ws;                 ws += (size_t)BB * LL * FF * 2;
    int* idx_map        = (int*)ws;

    prep_w_kernel<<<512, 256, 0, stream>>>(c1w, c2w, wT1, wT2);

    const int conv_grid = BB * (LL / MT);   // 768
    conv_mfma_kernel<false><<<conv_grid, 256, 0, stream>>>(
        x, wT1, c1b, g1, b1, nullptr, nullptr, h1b, nullptr);
    conv_mfma_kernel<true><<<conv_grid, 256, 0, stream>>>(
        h1b, wT2, c2b, g2, b2, lw, lb, nullptr, out_dur);

    scan_kernel<<<BB, 256, 0, stream>>>(target, out_dpo, idx_map);
    gather_kernel<<<BB * TT / 4, 256, 0, stream>>>(x, idx_map, out0);
}

// Round 5
// 234.498 us; speedup vs baseline: 2.0628x; 1.1350x over previous
//
#include <hip/hip_runtime.h>
#include <hip/hip_bf16.h>
#include <math.h>

// Problem constants (fixed by the reference)
#define BB 32
#define LL 768
#define DD 256
#define FF 256
#define TT 3072
#define MT 32              // output rows (l positions) per conv block
#define OS 257             // output-tile row stride (floats): odd -> column access conflict-free

typedef __attribute__((ext_vector_type(8))) short bf16x8;
typedef __attribute__((ext_vector_type(4))) float f32x4;

__device__ inline unsigned short f2b(float f) {
    union { float f; unsigned u; } v; v.f = f;
    unsigned r = (v.u + 0x7FFF + ((v.u >> 16) & 1)) >> 16;  // RNE
    return (unsigned short)r;
}

// ---------------------------------------------------------------------------
// Weight prep into FRAGMENT-MAJOR layout:
//   wQ[s*8192 + n*32 + q*8 + j] = bf16(w[kc][cin][n])
//   s = kc*8 + c8 (K-step), cin = c8*32 + q*8 + j
// so a B-fragment load (step s, wave, nt) is one contiguous 1 KB wave-burst.
// ---------------------------------------------------------------------------
__global__ __launch_bounds__(256) void prep_w_kernel(
    const float* __restrict__ w1, const float* __restrict__ w2,
    unsigned short* __restrict__ wQ1, unsigned short* __restrict__ wQ2)
{
    const int layer = blockIdx.x / 24;
    const int s  = blockIdx.x % 24;
    const int kc = s >> 3, c8 = s & 7;
    const float* __restrict__ w = layer ? w2 : w1;
    unsigned short* __restrict__ o = (layer ? wQ2 : wQ1) + s * 8192 + threadIdx.x * 32;
    const int n = threadIdx.x;

    alignas(16) unsigned short tmp[32];
#pragma unroll
    for (int q = 0; q < 4; ++q)
#pragma unroll
        for (int j = 0; j < 8; ++j) {
            const int cin = c8 * 32 + q * 8 + j;
            tmp[q * 8 + j] = f2b(w[((size_t)(kc * 256 + cin)) * 256 + n]);
        }
#pragma unroll
    for (int i = 0; i < 4; ++i)
        *reinterpret_cast<uint4*>(o + i * 8) = *reinterpret_cast<const uint4*>(tmp + i * 8);
}

// ---------------------------------------------------------------------------
// Fused Conv1d(k=3,pad=1) + ReLU + LayerNorm (+ linear->exp head on SECOND)
// bf16 MFMA GEMM: M-tile=32 rows, N=256 (full width), K=768.
// A staged in LDS fragment-major, duplicated per tap (conflict-free b128).
// B streamed from fragment-major wQ (coalesced 1KB bursts, L2-resident).
// Epilogue: round-2-verbatim (per-column LN + explicit head).
// ---------------------------------------------------------------------------
template <bool SECOND>
__global__ __launch_bounds__(256) void conv_mfma_kernel(
    const void* __restrict__ in_,              // conv1: float*, conv2: bf16(ushort)*
    const unsigned short* __restrict__ wQ,     // fragment-major weights
    const float* __restrict__ cbias,           // [256]
    const float* __restrict__ g,               // [256]
    const float* __restrict__ be,              // [256]
    const float* __restrict__ lin_w,           // [256] (SECOND)
    const float* __restrict__ lin_b,           // [1]   (SECOND)
    unsigned short* __restrict__ out_h,        // bf16 [B,L,256] (first layer)
    float* __restrict__ out_dur)               // [B,L] (SECOND)
{
    __shared__ union {
        unsigned short Af[48 * 64 * 8];        // 48 KB fragment-major A
        float outs[MT * OS];                   // 32.9 KB output tile
    } sm;
    __shared__ float red[4][MT][2];
    __shared__ float fin[MT][2];

    const int tid  = threadIdx.x;
    const int b    = blockIdx.x / (LL / MT);
    const int l0   = (blockIdx.x % (LL / MT)) * MT;
    const int wave = tid >> 6, lane = tid & 63;
    const int quad = lane >> 4, l16 = lane & 15;

    // ---- stage A fragment-major (combo = (kc*8+c8)*2 + mt, 48 combos) ----
    for (int i = 0; i < 12; ++i) {
        const int combo = i * 4 + wave;
        const int mt = combo & 1;
        const int sc = combo >> 1;             // kc*8 + c8
        const int kc = sc >> 3, c8 = sc & 7;
        const int l  = l0 + mt * 16 + l16 + kc - 1;
        const int ch = c8 * 32 + quad * 8;
        bf16x8 val;
#pragma unroll
        for (int j = 0; j < 8; ++j) val[j] = 0;
        if (l >= 0 && l < LL) {
            if (!SECOND) {
                const float* p = (const float*)in_ + ((size_t)b * LL + l) * DD + ch;
                const float4 v0 = *reinterpret_cast<const float4*>(p);
                const float4 v1 = *reinterpret_cast<const float4*>(p + 4);
                val[0] = (short)f2b(v0.x); val[1] = (short)f2b(v0.y);
                val[2] = (short)f2b(v0.z); val[3] = (short)f2b(v0.w);
                val[4] = (short)f2b(v1.x); val[5] = (short)f2b(v1.y);
                val[6] = (short)f2b(v1.z); val[7] = (short)f2b(v1.w);
            } else {
                val = *reinterpret_cast<const bf16x8*>(
                    (const unsigned short*)in_ + ((size_t)b * LL + l) * DD + ch);
            }
        }
        *reinterpret_cast<bf16x8*>(&sm.Af[(combo * 64 + lane) * 8]) = val;
    }
    __syncthreads();

    // ---- K loop: 24 steps of 32 (plain loads; compiler pipelines) ----
    const unsigned short* aptr = &sm.Af[lane * 8];            // + s*1024 + mt*512
    const unsigned short* bptr = wQ + wave * 2048 + (l16 * 4 + quad) * 8;  // + s*8192 + nt*512

    f32x4 acc[2][4] = {};
    for (int s = 0; s < 24; ++s) {
        bf16x8 a[2], bb4[4];
#pragma unroll
        for (int mt = 0; mt < 2; ++mt)
            a[mt] = *reinterpret_cast<const bf16x8*>(aptr + s * 1024 + mt * 512);
#pragma unroll
        for (int nt = 0; nt < 4; ++nt)
            bb4[nt] = *reinterpret_cast<const bf16x8*>(bptr + (size_t)s * 8192 + nt * 512);
#pragma unroll
        for (int mt = 0; mt < 2; ++mt)
#pragma unroll
            for (int nt = 0; nt < 4; ++nt)
                acc[mt][nt] = __builtin_amdgcn_mfma_f32_16x16x32_bf16(
                    a[mt], bb4[nt], acc[mt][nt], 0, 0, 0);
    }
    __syncthreads();   // A-tile dead; reuse LDS for output tile

    // ---- scatter raw accumulators to LDS (C/D: col=lane&15, row=quad*4+reg) ----
#pragma unroll
    for (int mt = 0; mt < 2; ++mt)
#pragma unroll
        for (int nt = 0; nt < 4; ++nt)
#pragma unroll
            for (int r = 0; r < 4; ++r)
                sm.outs[(mt * 16 + quad * 4 + r) * OS + wave * 64 + nt * 16 + l16] =
                    acc[mt][nt][r];
    __syncthreads();

    // ---- round-2-verbatim epilogue: per-column bias/ReLU + LN + head ----
    const int col = tid;
    const float biasv = cbias[col];
    float vv[MT];
#pragma unroll
    for (int r = 0; r < MT; ++r)
        vv[r] = fmaxf(sm.outs[r * OS + col] + biasv, 0.f);

#pragma unroll
    for (int r = 0; r < MT; ++r) {
        float v = vv[r];
        float sum = v, sq = v * v;
        for (int off = 32; off > 0; off >>= 1) {
            sum += __shfl_down(sum, off, 64);
            sq  += __shfl_down(sq,  off, 64);
        }
        if (lane == 0) { red[wave][r][0] = sum; red[wave][r][1] = sq; }
    }
    __syncthreads();
    if (tid < MT) {
        const float sum = red[0][tid][0] + red[1][tid][0] + red[2][tid][0] + red[3][tid][0];
        const float sq  = red[0][tid][1] + red[1][tid][1] + red[2][tid][1] + red[3][tid][1];
        const float mu  = sum / FF;
        const float var = sq / FF - mu * mu;
        fin[tid][0] = mu;
        fin[tid][1] = rsqrtf(var + 1e-5f);
    }
    __syncthreads();

    const float gv  = g[col];
    const float bv  = be[col];
    const float lwv = SECOND ? lin_w[col] : 0.f;

#pragma unroll
    for (int r = 0; r < MT; ++r) {
        const float v = (vv[r] - fin[r][0]) * fin[r][1] * gv + bv;
        if (!SECOND) {
            out_h[((size_t)b * LL + l0 + r) * FF + col] = f2b(v);
        } else {
            float p = v * lwv;
            for (int off = 32; off > 0; off >>= 1) p += __shfl_down(p, off, 64);
            if (lane == 0) red[wave][r][0] = p;
        }
    }
    if (SECOND) {
        __syncthreads();
        if (tid < MT) {
            const float dp = red[0][tid][0] + red[1][tid][0] + red[2][tid][0]
                           + red[3][tid][0] + lin_b[0];
            out_dur[(size_t)b * LL + l0 + tid] = expf(dp);
        }
    }
}

// ---------------------------------------------------------------------------
// dpo + cumsum + scatter idx map.  One block per batch row.
// ---------------------------------------------------------------------------
__global__ __launch_bounds__(256) void scan_kernel(
    const int* __restrict__ target,    // [B, L]
    float* __restrict__ out_dpo,       // [B, L] (stored as float)
    int* __restrict__ idx_map)         // [B, T]
{
    __shared__ int tsum[256];
    const int b = blockIdx.x, tid = threadIdx.x;

    const int l = 3 * tid;
    const int v0 = target[b * LL + l];
    const int v1 = target[b * LL + l + 1];
    const int v2 = target[b * LL + l + 2];
    out_dpo[b * LL + l]     = (float)v0;
    out_dpo[b * LL + l + 1] = (float)v1;
    out_dpo[b * LL + l + 2] = (float)v2;

    const int s0 = v0, s1 = v0 + v1, s2 = v0 + v1 + v2;
    tsum[tid] = s2;
    __syncthreads();
    for (int off = 1; off < 256; off <<= 1) {
        int x = (tid >= off) ? tsum[tid - off] : 0;
        __syncthreads();
        tsum[tid] += x;
        __syncthreads();
    }
    const int excl = tsum[tid] - s2;

    for (int t = tid; t < TT; t += 256) idx_map[b * TT + t] = -1;
    __syncthreads();

    const int c0 = excl + s0, c1 = excl + s1, c2 = excl + s2;
    for (int t = excl; t < c0 && t < TT; ++t) idx_map[b * TT + t] = l;
    for (int t = c0;   t < c1 && t < TT; ++t) idx_map[b * TT + t] = l + 1;
    for (int t = c1;   t < c2 && t < TT; ++t) idx_map[b * TT + t] = l + 2;
}

// ---------------------------------------------------------------------------
// Gather: out[b,t,:] = x[b, idx_map[b][t], :]  (zeros when masked)
// ---------------------------------------------------------------------------
__global__ __launch_bounds__(256) void gather_kernel(
    const float* __restrict__ x,       // [B, L, 256]
    const int* __restrict__ idx_map,   // [B, T]
    float* __restrict__ out)           // [B, T, 256]
{
    const int wv = threadIdx.x >> 6, lane = threadIdx.x & 63;
    const int row = blockIdx.x * 4 + wv;          // row in [0, B*T)
    const int b = row / TT, t = row - b * TT;
    const int idx = idx_map[b * TT + t];
    float4 val = make_float4(0.f, 0.f, 0.f, 0.f);
    if (idx >= 0)
        val = reinterpret_cast<const float4*>(x)[(size_t)(b * LL + idx) * (DD / 4) + lane];
    reinterpret_cast<float4*>(out)[(size_t)row * (DD / 4) + lane] = val;
}

// ---------------------------------------------------------------------------
extern "C" void kernel_launch(void* const* d_in, const int* in_sizes, int n_in,
                              void* d_out, int out_size, void* d_ws, size_t ws_size,
                              hipStream_t stream)
{
    const float* x      = (const float*)d_in[0];
    const int*   target = (const int*)  d_in[1];
    const float* c1w = (const float*)d_in[3];
    const float* c1b = (const float*)d_in[4];
    const float* g1  = (const float*)d_in[5];
    const float* b1  = (const float*)d_in[6];
    const float* c2w = (const float*)d_in[7];
    const float* c2b = (const float*)d_in[8];
    const float* g2  = (const float*)d_in[9];
    const float* b2  = (const float*)d_in[10];
    const float* lw  = (const float*)d_in[11];
    const float* lb  = (const float*)d_in[12];

    float* out0    = (float*)d_out;                       // [B, T, 256]
    float* out_dpo = out0 + (size_t)BB * TT * DD;         // [B, L]
    float* out_dur = out_dpo + (size_t)BB * LL;           // [B, L]

    // workspace layout
    char* ws = (char*)d_ws;
    unsigned short* wQ1 = (unsigned short*)ws;                 ws += (size_t)24 * 8192 * 2;
    unsigned short* wQ2 = (unsigned short*)ws;                 ws += (size_t)24 * 8192 * 2;
    unsigned short* h1b = (unsigned short*)ws;                 ws += (size_t)BB * LL * FF * 2;
    int* idx_map        = (int*)ws;

    prep_w_kernel<<<48, 256, 0, stream>>>(c1w, c2w, wQ1, wQ2);

    const int conv_grid = BB * (LL / MT);   // 768
    conv_mfma_kernel<false><<<conv_grid, 256, 0, stream>>>(
        x, wQ1, c1b, g1, b1, nullptr, nullptr, h1b, nullptr);
    conv_mfma_kernel<true><<<conv_grid, 256, 0, stream>>>(
        h1b, wQ2, c2b, g2, b2, lw, lb, nullptr, out_dur);

    scan_kernel<<<BB, 256, 0, stream>>>(target, out_dpo, idx_map);
    gather_kernel<<<BB * TT / 4, 256, 0, stream>>>(x, idx_map, out0);
}